// Round 2
// baseline (361.974 us; speedup 1.0000x reference)
//
#include <hip/hip_runtime.h>
#include <math.h>

#define INV_SQRT2f 0.70710678118654752440f
#define PI_OVER_4f 0.78539816339744830962f

// ---- gate helpers: state fully in registers, compile-time strides ----

// RY on qubit with index-stride D (D = 8 >> qubit).
template<int D>
__device__ __forceinline__ void ry_gate(float st[16], float c, float s) {
#pragma unroll
    for (int i = 0; i < 16; ++i) {
        if ((i & D) == 0) {
            float a = st[i], b = st[i | D];
            st[i]     = c * a - s * b;
            st[i | D] = s * a + c * b;
        }
    }
}

// CNOT control-stride DC, target-stride DT: register permutation.
template<int DC, int DT>
__device__ __forceinline__ void cnot_gate(float st[16]) {
#pragma unroll
    for (int i = 0; i < 16; ++i) {
        if ((i & DC) && !(i & DT)) {
            float t = st[i]; st[i] = st[i | DT]; st[i | DT] = t;
        }
    }
}

// async global->LDS: 64 lanes x 16B = 1KB contiguous. gsrc is per-lane
// (already includes +lane*4 floats), ldst must be wave-uniform.
__device__ __forceinline__ void stage1k(const float* gsrc, float* ldst) {
    __builtin_amdgcn_global_load_lds(
        (const __attribute__((address_space(1))) unsigned int*)gsrc,
        (__attribute__((address_space(3))) unsigned int*)ldst,
        16, 0, 0);
}

// One wave handles 16 rows: LDS-staged GEMV + per-lane circuit.
__global__ __launch_bounds__(256, 4) void qnet_fused_kernel(
    const float* __restrict__ X,      // [B, 512]
    const float* __restrict__ preW,   // [4, 512]
    const float* __restrict__ preB,   // [4]
    const float* __restrict__ qp,     // [60]
    const float* __restrict__ postW,  // [2, 4]
    const float* __restrict__ postB,  // [2]
    float* __restrict__ out,          // [B, 2]
    int B)
{
    // per-wave double buffer: [wave][buf][2 rows x 512 floats] = 32 KB total
    __shared__ __align__(16) float xs[4][2][1024];
    __shared__ float cs[6][4][2];     // cos/sin of q_weights[k+1][w] * 0.5

    const int tid  = threadIdx.x;
    const int lane = tid & 63;
    const int wid  = tid >> 6;

    if (tid < 24) {
        float ang = qp[tid + 4] * 0.5f;   // (k+1)*4 + w == tid + 4
        cs[tid >> 2][tid & 3][0] = cosf(ang);
        cs[tid >> 2][tid & 3][1] = sinf(ang);
    }
    __syncthreads();

    const int row0 = (blockIdx.x * 4 + wid) * 16;

    // Per-lane weight slice: cols [4L,4L+4) and [256+4L,256+4L+4) of 4 rows.
    float4 wa[4], wb[4];
#pragma unroll
    for (int o = 0; o < 4; ++o) {
        wa[o] = *(const float4*)(preW + o * 512 + 4 * lane);
        wb[o] = *(const float4*)(preW + o * 512 + 256 + 4 * lane);
    }
    // Small uniform params now, so the loop's vmcnt domain stays clean.
    const float pb0 = preB[0], pb1 = preB[1], pb2 = preB[2], pb3 = preB[3];
    const float w00 = postW[0], w01 = postW[1], w02 = postW[2], w03 = postW[3];
    const float w10 = postW[4], w11 = postW[5], w12 = postW[6], w13 = postW[7];
    const float ob0 = postB[0], ob1 = postB[1];
    // Drain everything issued so far: loop vmcnt counting is exact after this.
    asm volatile("s_waitcnt vmcnt(0)" ::: "memory");

    const float* Xw = X + (size_t)row0 * 512;
    float* ldsw = &xs[wid][0][0];

    float P[4][4];    // partials for current 4-row group (compile-time idx)
    float Bg[4][4];   // fully-reduced per-group values (compile-time idx)

    // stage chunk c (2 rows = 4KB) into buffer b
#define STAGE(c, b) do {                                         \
        const float* _s = Xw + (c) * 1024 + lane * 4;            \
        float* _d = ldsw + (b) * 1024;                           \
        stage1k(_s,        _d);                                  \
        stage1k(_s + 256,  _d + 256);                            \
        stage1k(_s + 512,  _d + 512);                            \
        stage1k(_s + 768,  _d + 768);                            \
    } while (0)

    STAGE(0, 0);

#pragma unroll
    for (int c = 0; c < 8; ++c) {
        __builtin_amdgcn_sched_barrier(0);   // pin stage/read order
        if (c < 7) {
            STAGE(c + 1, (c + 1) & 1);
            asm volatile("s_waitcnt vmcnt(4)" ::: "memory");  // chunk c ready
        } else {
            asm volatile("s_waitcnt vmcnt(0)" ::: "memory");
        }
        const float* xbuf = ldsw + (c & 1) * 1024;
#pragma unroll
        for (int j = 0; j < 2; ++j) {
            float4 xa = *(const float4*)(xbuf + j * 512 + 4 * lane);
            float4 xv = *(const float4*)(xbuf + j * 512 + 256 + 4 * lane);
            const int jj = (c & 1) * 2 + j;   // compile-time (both unrolled)
#pragma unroll
            for (int o = 0; o < 4; ++o) {
                P[jj][o] = xa.x*wa[o].x + xa.y*wa[o].y + xa.z*wa[o].z + xa.w*wa[o].w
                         + xv.x*wb[o].x + xv.y*wb[o].y + xv.z*wb[o].z + xv.w*wb[o].w;
            }
        }
        if (c & 1) {
            // 4-row group complete: paired butterfly reduce.
            const int g = c >> 1;
            const bool b1 = lane & 1, b2 = lane & 2;
#pragma unroll
            for (int o = 0; o < 4; ++o) {
                float s01 = b1 ? P[0][o] : P[1][o];
                float k01 = b1 ? P[1][o] : P[0][o];
                float A0  = k01 + __shfl_xor(s01, 1);   // lane bit0 = row bit0
                float s23 = b1 ? P[2][o] : P[3][o];
                float k23 = b1 ? P[3][o] : P[2][o];
                float A1  = k23 + __shfl_xor(s23, 1);
                float sb  = b2 ? A0 : A1;
                float kb  = b2 ? A1 : A0;
                float Bv  = kb + __shfl_xor(sb, 2);     // lane bit1 = row bit1
                Bv += __shfl_xor(Bv, 4);
                Bv += __shfl_xor(Bv, 8);
                Bv += __shfl_xor(Bv, 16);
                Bv += __shfl_xor(Bv, 32);
                Bg[g][o] = Bv;   // lane L holds row 4g + (L&3), full 64-lane sum
            }
        }
    }
#undef STAGE

    // ---- phase 2: every lane simulates row  4*((lane>>2)&3) + (lane&3) ----
    // For lanes 0..15 that is exactly row0+lane; lanes 16+ are redundant.
    const bool sl0 = (lane >> 2) & 1;
    const bool sl1 = (lane >> 2) & 2;
#define PICK(o) (sl1 ? (sl0 ? Bg[3][o] : Bg[2][o]) : (sl0 ? Bg[1][o] : Bg[0][o]))
    float pr0 = PICK(0) + pb0;
    float pr1 = PICK(1) + pb1;
    float pr2 = PICK(2) + pb2;
    float pr3 = PICK(3) + pb3;
#undef PICK

    float u[4], v[4];
    {
        float prs[4] = {pr0, pr1, pr2, pr3};
#pragma unroll
        for (int w = 0; w < 4; ++w) {
            float t = tanhf(prs[w]);
            float h = t * PI_OVER_4f;        // theta/2 = tanh(pre) * pi/4
            float sh, ch;
            __sincosf(h, &sh, &ch);
            u[w] = (ch - sh) * INV_SQRT2f;   // amplitude for bit=0 (after H,RY)
            v[w] = (ch + sh) * INV_SQRT2f;   // amplitude for bit=1
        }
    }

    // Product state after H^4 + input RY layer. i = b0*8 + b1*4 + b2*2 + b3.
    float st[16];
#pragma unroll
    for (int i = 0; i < 16; ++i) {
        st[i] = ((i & 8) ? v[0] : u[0]) * ((i & 4) ? v[1] : u[1])
              * ((i & 2) ? v[2] : u[2]) * ((i & 1) ? v[3] : u[3]);
    }

#pragma unroll
    for (int k = 0; k < 6; ++k) {
        cnot_gate<8, 4>(st);   // CNOT(0,1)
        cnot_gate<2, 1>(st);   // CNOT(2,3)
        cnot_gate<4, 2>(st);   // CNOT(1,2)
        ry_gate<8>(st, cs[k][0][0], cs[k][0][1]);
        ry_gate<4>(st, cs[k][1][0], cs[k][1][1]);
        ry_gate<2>(st, cs[k][2][0], cs[k][2][1]);
        ry_gate<1>(st, cs[k][3][0], cs[k][3][1]);
    }

    float z0 = 0.f, z1 = 0.f, z2 = 0.f, z3 = 0.f;
#pragma unroll
    for (int i = 0; i < 16; ++i) {
        float q = st[i] * st[i];
        z0 += (i & 8) ? -q : q;
        z1 += (i & 4) ? -q : q;
        z2 += (i & 2) ? -q : q;
        z3 += (i & 1) ? -q : q;
    }

    float o0 = ob0 + w00*z0 + w01*z1 + w02*z2 + w03*z3;
    float o1 = ob1 + w10*z0 + w11*z1 + w12*z2 + w13*z3;

    if (lane < 16) {
        const int row = row0 + lane;
        if (row < B) {
            *(float2*)(out + (size_t)row * 2) = make_float2(o0, o1);
        }
    }
}

extern "C" void kernel_launch(void* const* d_in, const int* in_sizes, int n_in,
                              void* d_out, int out_size, void* d_ws, size_t ws_size,
                              hipStream_t stream) {
    const float* X     = (const float*)d_in[0];
    const float* preW  = (const float*)d_in[1];
    const float* preB  = (const float*)d_in[2];
    const float* qp    = (const float*)d_in[3];
    const float* postW = (const float*)d_in[4];
    const float* postB = (const float*)d_in[5];
    float* out = (float*)d_out;

    const int B = in_sizes[0] / 512;      // 131072
    const int grid = (B + 63) / 64;       // 64 rows/block = 4 waves x 16 rows

    hipLaunchKernelGGL(qnet_fused_kernel, dim3(grid), dim3(256), 0, stream,
                       X, preW, preB, qp, postW, postB, out, B);
}